// Round 2
// baseline (392.744 us; speedup 1.0000x reference)
//
#include <hip/hip_runtime.h>

// ---------------------------------------------------------------------------
// BiasedAttention fused pipeline (MI355X / gfx950)  — R1: swapped-QK^T attn
//   x[8,1024,1024] f32 -> LN -> bf16
//   qkv = xn @ Wqkv (bf16 MFMA, fp32 acc; Q cols pre-scaled 0.125)
//   flash attention w/ additive bias, swapped-operand softmax (lane-local rows)
//   out = attn_out @ Wout -> f32 d_out
// Workspace layout (bytes):
//   xn      bf16  8192*1024*2  = 16777216   @ 0
//   wqkv_t  bf16  3072*1024*2  =  6291456   @ 16777216
//   wout_t  bf16  1024*1024*2  =  2097152   @ 23068672
//   qkv     bf16  8192*3072*2  = 50331648   @ 25165824
//   aout    bf16  8192*1024*2  = 16777216   @ 75497472
// ---------------------------------------------------------------------------

#define DIM    1024
#define HEADS  16
#define DHEAD  64
#define INNER  1024
#define SEQ    1024
#define BATCH  8
#define QKV3   3072

typedef __bf16 bf16x8 __attribute__((ext_vector_type(8)));
typedef float f32x4 __attribute__((ext_vector_type(4)));
typedef unsigned short u16x8 __attribute__((ext_vector_type(8)));
typedef unsigned short u16x4 __attribute__((ext_vector_type(4)));

typedef __attribute__((address_space(1))) const unsigned int as1_uint;
typedef __attribute__((address_space(3))) unsigned int as3_uint;

static __device__ inline unsigned short f2bf(float f) {
  unsigned int u = __float_as_uint(f);
  u = (u + 0x7FFFu + ((u >> 16) & 1u)) >> 16;  // RNE
  return (unsigned short)u;
}
// compiler-cast version for hot paths (emits v_cvt_pk_bf16_f32 when paired)
static __device__ inline unsigned short f2bf_fast(float f) {
  __bf16 h = (__bf16)f;
  return __builtin_bit_cast(unsigned short, h);
}

// ---------------------------------------------------------------------------
// 1. LayerNorm fp32 -> bf16
// ---------------------------------------------------------------------------
__global__ __launch_bounds__(256) void ln_bf16_kernel(
    const float* __restrict__ x, const float* __restrict__ gamma,
    const float* __restrict__ beta, unsigned short* __restrict__ xn) {
  int row = blockIdx.x;
  int tid = threadIdx.x;
  const float4* xr = reinterpret_cast<const float4*>(x + (size_t)row * DIM);
  float4 v = xr[tid];
  float s = v.x + v.y + v.z + v.w;
  float s2 = v.x * v.x + v.y * v.y + v.z * v.z + v.w * v.w;
#pragma unroll
  for (int m = 32; m; m >>= 1) {
    s += __shfl_xor(s, m, 64);
    s2 += __shfl_xor(s2, m, 64);
  }
  __shared__ float red[2][4];
  int wid = tid >> 6, lane = tid & 63;
  if (lane == 0) { red[0][wid] = s; red[1][wid] = s2; }
  __syncthreads();
  s = red[0][0] + red[0][1] + red[0][2] + red[0][3];
  s2 = red[1][0] + red[1][1] + red[1][2] + red[1][3];
  float mu = s * (1.0f / DIM);
  float var = s2 * (1.0f / DIM) - mu * mu;
  float rstd = rsqrtf(var + 1e-5f);
  float4 g = reinterpret_cast<const float4*>(gamma)[tid];
  float4 b = reinterpret_cast<const float4*>(beta)[tid];
  u16x4 o;
  o[0] = f2bf((v.x - mu) * rstd * g.x + b.x);
  o[1] = f2bf((v.y - mu) * rstd * g.y + b.y);
  o[2] = f2bf((v.z - mu) * rstd * g.z + b.z);
  o[3] = f2bf((v.w - mu) * rstd * g.w + b.w);
  *reinterpret_cast<u16x4*>(xn + (size_t)row * DIM + tid * 4) = o;
}

// ---------------------------------------------------------------------------
// 2. Transpose + fp32->bf16:  W[R][C] -> Wt[C][R]; rows < scale_rows get *0.125
// ---------------------------------------------------------------------------
__global__ __launch_bounds__(256) void transpose_cvt(
    const float* __restrict__ W, unsigned short* __restrict__ Wt, int R, int C,
    int scale_rows) {
  __shared__ float tb[32][33];
  int c0 = blockIdx.x * 32, r0 = blockIdx.y * 32;
  int tx = threadIdx.x, ty = threadIdx.y;  // (32, 8)
#pragma unroll
  for (int i = 0; i < 4; ++i)
    tb[ty + i * 8][tx] = W[(size_t)(r0 + ty + i * 8) * C + c0 + tx];
  __syncthreads();
#pragma unroll
  for (int i = 0; i < 4; ++i) {
    int orow = c0 + ty + i * 8;
    float v = tb[tx][ty + i * 8];
    if (orow < scale_rows) v *= 0.125f;
    Wt[(size_t)orow * R + r0 + tx] = f2bf(v);
  }
}

// ---------------------------------------------------------------------------
// 3. GEMM  C[M,N] = A[M,K] @ Bt[N,K]^T   (bf16 in, fp32 acc) — m97 structure
// ---------------------------------------------------------------------------
template <bool F32OUT>
__global__ __launch_bounds__(256) void gemm_bt(
    const unsigned short* __restrict__ A, const unsigned short* __restrict__ Bt,
    void* __restrict__ Cout, int M, int N, int K) {
  __shared__ unsigned short As[128 * 64];
  __shared__ unsigned short Bs[128 * 64];
  int nb = N >> 7;
  int bm = blockIdx.x / nb, bn = blockIdx.x % nb;
  int tid = threadIdx.x, wid = tid >> 6, lane = tid & 63;
  int wr = wid >> 1, wc = wid & 1;
  int lg = lane >> 4, lr = lane & 15;
  f32x4 acc[4][4] = {};
  const unsigned short* Ablk = A + (size_t)(bm * 128) * K;
  const unsigned short* Bblk = Bt + (size_t)(bn * 128) * K;
  int srow = wid * 32 + (lane >> 3);
  int scol = (lane & 7) * 8;
  for (int kt = 0; kt < K; kt += 64) {
#pragma unroll
    for (int t = 0; t < 4; ++t) {
      int r = srow + t * 8;
      __builtin_amdgcn_global_load_lds(
          (as1_uint*)(Ablk + (size_t)r * K + kt + scol),
          (as3_uint*)(&As[(wid * 32 + t * 8) * 64]), 16, 0, 0);
      __builtin_amdgcn_global_load_lds(
          (as1_uint*)(Bblk + (size_t)r * K + kt + scol),
          (as3_uint*)(&Bs[(wid * 32 + t * 8) * 64]), 16, 0, 0);
    }
    __syncthreads();
#pragma unroll
    for (int kk = 0; kk < 2; ++kk) {
      bf16x8 af[4], bfr[4];
#pragma unroll
      for (int mi = 0; mi < 4; ++mi)
        af[mi] = *reinterpret_cast<const bf16x8*>(
            &As[(wr * 64 + mi * 16 + lr) * 64 + kk * 32 + lg * 8]);
#pragma unroll
      for (int ni = 0; ni < 4; ++ni)
        bfr[ni] = *reinterpret_cast<const bf16x8*>(
            &Bs[(wc * 64 + ni * 16 + lr) * 64 + kk * 32 + lg * 8]);
#pragma unroll
      for (int mi = 0; mi < 4; ++mi)
#pragma unroll
        for (int ni = 0; ni < 4; ++ni)
          acc[mi][ni] = __builtin_amdgcn_mfma_f32_16x16x32_bf16(
              af[mi], bfr[ni], acc[mi][ni], 0, 0, 0);
    }
    __syncthreads();
  }
#pragma unroll
  for (int mi = 0; mi < 4; ++mi) {
    int row = bm * 128 + wr * 64 + mi * 16 + lg * 4;
#pragma unroll
    for (int ni = 0; ni < 4; ++ni) {
      int col = bn * 128 + wc * 64 + ni * 16 + lr;
#pragma unroll
      for (int j = 0; j < 4; ++j) {
        if (F32OUT)
          ((float*)Cout)[(size_t)(row + j) * N + col] = acc[mi][ni][j];
        else
          ((unsigned short*)Cout)[(size_t)(row + j) * N + col] = f2bf(acc[mi][ni][j]);
      }
    }
  }
}

// ---------------------------------------------------------------------------
// 4. Flash attention, swapped-operand form.
//    S^T = mfma(K_frag, Q_frag): lane holds 16 scores of ONE q-row (col=lr).
//    Softmax: in-reg tree + 2 shfl. P stored [q][kv] in per-wave LDS (b64
//    packed writes), read as PV B-operand. PV: O^T = mfma(V^T, P^T); m/l/alpha
//    stay lane-local. K direct from global (L2-resident); V double-buffered
//    LDS transpose stage, prefetched one tile ahead. One barrier per tile.
// ---------------------------------------------------------------------------
__global__ __launch_bounds__(256) void attn_kernel(
    const unsigned short* __restrict__ qkv, const float* __restrict__ bias,
    unsigned short* __restrict__ aout) {
  int id = blockIdx.x;           // id = b + 8*(qt + 8*h)
  int b = id & 7, qt = (id >> 3) & 7, h = id >> 6;
  int tid = threadIdx.x, wid = tid >> 6, lane = tid & 63;
  int lg = lane >> 4, lr = lane & 15;

  __shared__ unsigned short Vt[2][64 * 72];   // [d][kv] transposed, dbuf
  __shared__ unsigned short Ps[4][32 * 72];   // per-wave P [q][kv]

  const unsigned short* qbase = qkv + (size_t)(b * SEQ) * QKV3 + h * 64;
  const unsigned short* kbase = qbase + INNER;
  const unsigned short* vbase = qbase + 2 * INNER;
  const float* biash = bias + (size_t)h * SEQ * SEQ;

  int q0 = qt * 128 + wid * 32;

  // Q fragments (B-operand layout: col=lr=q, k=d contiguous). Pre-scaled.
  bf16x8 qf[2][2];
#pragma unroll
  for (int mi = 0; mi < 2; ++mi)
#pragma unroll
    for (int kk = 0; kk < 2; ++kk)
      qf[mi][kk] = *reinterpret_cast<const bf16x8*>(
          qbase + (size_t)(q0 + mi * 16 + lr) * QKV3 + kk * 32 + lg * 8);

  const float* brow[2];
#pragma unroll
  for (int mi = 0; mi < 2; ++mi)
    brow[mi] = biash + (size_t)(q0 + mi * 16 + lr) * SEQ;

  // V staging indexing: each thread owns kv-row (tid&63), d-chunks (tid>>6)+{0,4}
  int vrow = tid & 63;
  int vchunk = tid >> 6;
  u16x8 vreg[2];
#pragma unroll
  for (int it = 0; it < 2; ++it)
    vreg[it] = *reinterpret_cast<const u16x8*>(
        vbase + (size_t)vrow * QKV3 + (vchunk + it * 4) * 8);

  f32x4 oacc[2][4] = {};
  float mrun[2] = {-1e30f, -1e30f}, lrun[2] = {0.f, 0.f};

  for (int t = 0; t < 16; ++t) {
    int cur = t & 1;
    // ---- scatter-write prefetched V regs into Vt[cur] (transpose) ----
#pragma unroll
    for (int it = 0; it < 2; ++it)
#pragma unroll
      for (int i = 0; i < 8; ++i)
        Vt[cur][((vchunk + it * 4) * 8 + i) * 72 + vrow] = vreg[it][i];
    __syncthreads();

    // ---- K fragments direct from global (A-operand: row=kv=lr) ----
    bf16x8 kf[4][2];
#pragma unroll
    for (int kb = 0; kb < 4; ++kb)
#pragma unroll
      for (int kk = 0; kk < 2; ++kk)
        kf[kb][kk] = *reinterpret_cast<const bf16x8*>(
            kbase + (size_t)(t * 64 + kb * 16 + lr) * QKV3 + kk * 32 + lg * 8);

    // ---- bias: float4 per (mi, kvblk) ----
    f32x4 bv[2][4];
#pragma unroll
    for (int mi = 0; mi < 2; ++mi)
#pragma unroll
      for (int kb = 0; kb < 4; ++kb)
        bv[mi][kb] = *reinterpret_cast<const f32x4*>(
            brow[mi] + t * 64 + kb * 16 + lg * 4);

    // ---- prefetch next V tile ----
    if (t < 15) {
#pragma unroll
      for (int it = 0; it < 2; ++it)
        vreg[it] = *reinterpret_cast<const u16x8*>(
            vbase + (size_t)((t + 1) * 64 + vrow) * QKV3 + (vchunk + it * 4) * 8);
    }

    // ---- S^T = K @ Q^T ----
    f32x4 s[2][4] = {};
#pragma unroll
    for (int kk = 0; kk < 2; ++kk)
#pragma unroll
      for (int kb = 0; kb < 4; ++kb)
#pragma unroll
        for (int mi = 0; mi < 2; ++mi)
          s[mi][kb] = __builtin_amdgcn_mfma_f32_16x16x32_bf16(
              kf[kb][kk], qf[mi][kk], s[mi][kb], 0, 0, 0);

    // ---- + bias ----
#pragma unroll
    for (int mi = 0; mi < 2; ++mi)
#pragma unroll
      for (int kb = 0; kb < 4; ++kb)
#pragma unroll
        for (int j = 0; j < 4; ++j)
          s[mi][kb][j] += bv[mi][kb][j];

    // ---- online softmax: lane-local row, in-reg tree + 2 shfl ----
    float alpha[2];
#pragma unroll
    for (int mi = 0; mi < 2; ++mi) {
      float t0 = fmaxf(fmaxf(s[mi][0][0], s[mi][0][1]), fmaxf(s[mi][0][2], s[mi][0][3]));
      float t1 = fmaxf(fmaxf(s[mi][1][0], s[mi][1][1]), fmaxf(s[mi][1][2], s[mi][1][3]));
      float t2 = fmaxf(fmaxf(s[mi][2][0], s[mi][2][1]), fmaxf(s[mi][2][2], s[mi][2][3]));
      float t3 = fmaxf(fmaxf(s[mi][3][0], s[mi][3][1]), fmaxf(s[mi][3][2], s[mi][3][3]));
      float rm = fmaxf(fmaxf(t0, t1), fmaxf(t2, t3));
      rm = fmaxf(rm, __shfl_xor(rm, 16, 64));
      rm = fmaxf(rm, __shfl_xor(rm, 32, 64));
      float mnew = fmaxf(mrun[mi], rm);
      alpha[mi] = __expf(mrun[mi] - mnew);
      mrun[mi] = mnew;
      float ls = 0.f;
#pragma unroll
      for (int kb = 0; kb < 4; ++kb) {
        float e0 = __expf(s[mi][kb][0] - mnew);
        float e1 = __expf(s[mi][kb][1] - mnew);
        float e2 = __expf(s[mi][kb][2] - mnew);
        float e3 = __expf(s[mi][kb][3] - mnew);
        s[mi][kb][0] = e0; s[mi][kb][1] = e1;
        s[mi][kb][2] = e2; s[mi][kb][3] = e3;
        ls += (e0 + e1) + (e2 + e3);
      }
      ls += __shfl_xor(ls, 16, 64);
      ls += __shfl_xor(ls, 32, 64);
      lrun[mi] = lrun[mi] * alpha[mi] + ls;
    }

    // ---- P -> per-wave LDS [q][kv], packed b64 writes ----
#pragma unroll
    for (int mi = 0; mi < 2; ++mi)
#pragma unroll
      for (int kb = 0; kb < 4; ++kb) {
        u16x4 pk;
        pk[0] = f2bf_fast(s[mi][kb][0]);
        pk[1] = f2bf_fast(s[mi][kb][1]);
        pk[2] = f2bf_fast(s[mi][kb][2]);
        pk[3] = f2bf_fast(s[mi][kb][3]);
        *reinterpret_cast<u16x4*>(
            &Ps[wid][(mi * 16 + lr) * 72 + kb * 16 + lg * 4]) = pk;
      }
    asm volatile("s_waitcnt lgkmcnt(0)" ::: "memory");
    __builtin_amdgcn_sched_barrier(0);

    // ---- rescale O ----
#pragma unroll
    for (int mi = 0; mi < 2; ++mi)
#pragma unroll
      for (int db = 0; db < 4; ++db)
#pragma unroll
        for (int j = 0; j < 4; ++j)
          oacc[mi][db][j] *= alpha[mi];

    // ---- O^T += V^T @ P^T ----
#pragma unroll
    for (int k2 = 0; k2 < 2; ++k2) {
      bf16x8 va[4], pb[2];
#pragma unroll
      for (int db = 0; db < 4; ++db)
        va[db] = *reinterpret_cast<const bf16x8*>(
            &Vt[cur][(db * 16 + lr) * 72 + k2 * 32 + lg * 8]);
#pragma unroll
      for (int mi = 0; mi < 2; ++mi)
        pb[mi] = *reinterpret_cast<const bf16x8*>(
            &Ps[wid][(mi * 16 + lr) * 72 + k2 * 32 + lg * 8]);
#pragma unroll
      for (int mi = 0; mi < 2; ++mi)
#pragma unroll
        for (int db = 0; db < 4; ++db)
          oacc[mi][db] = __builtin_amdgcn_mfma_f32_16x16x32_bf16(
              va[db], pb[mi], oacc[mi][db], 0, 0, 0);
    }
  }

  // ---- epilogue: O^T / l -> aout bf16 (b64 packed stores) ----
#pragma unroll
  for (int mi = 0; mi < 2; ++mi) {
    float inv = 1.0f / lrun[mi];
    size_t row = (size_t)(b * SEQ + q0 + mi * 16 + lr) * INNER + h * 64;
#pragma unroll
    for (int db = 0; db < 4; ++db) {
      u16x4 o;
      o[0] = f2bf_fast(oacc[mi][db][0] * inv);
      o[1] = f2bf_fast(oacc[mi][db][1] * inv);
      o[2] = f2bf_fast(oacc[mi][db][2] * inv);
      o[3] = f2bf_fast(oacc[mi][db][3] * inv);
      *reinterpret_cast<u16x4*>(&aout[row + db * 16 + lg * 4]) = o;
    }
  }
}

// ---------------------------------------------------------------------------
extern "C" void kernel_launch(void* const* d_in, const int* in_sizes, int n_in,
                              void* d_out, int out_size, void* d_ws, size_t ws_size,
                              hipStream_t stream) {
  const float* x = (const float*)d_in[0];
  const float* gamma = (const float*)d_in[1];
  const float* beta = (const float*)d_in[2];
  const float* w_qkv = (const float*)d_in[3];
  const float* w_out = (const float*)d_in[4];
  const float* bias = (const float*)d_in[5];

  char* ws = (char*)d_ws;
  unsigned short* xn = (unsigned short*)(ws);
  unsigned short* wqkv_t = (unsigned short*)(ws + 16777216);
  unsigned short* wout_t = (unsigned short*)(ws + 23068672);
  unsigned short* qkvb = (unsigned short*)(ws + 25165824);
  unsigned short* aout = (unsigned short*)(ws + 75497472);

  ln_bf16_kernel<<<BATCH * SEQ, 256, 0, stream>>>(x, gamma, beta, xn);
  // Q out-features (rows [0,1024) of wqkv_t) pre-scaled by DHEAD^-0.5 = 0.125
  transpose_cvt<<<dim3(QKV3 / 32, DIM / 32), dim3(32, 8), 0, stream>>>(
      w_qkv, wqkv_t, DIM, QKV3, INNER);
  transpose_cvt<<<dim3(DIM / 32, INNER / 32), dim3(32, 8), 0, stream>>>(
      w_out, wout_t, INNER, DIM, 0);
  gemm_bt<false><<<(BATCH * SEQ / 128) * (QKV3 / 128), 256, 0, stream>>>(
      xn, wqkv_t, (void*)qkvb, BATCH * SEQ, QKV3, DIM);
  attn_kernel<<<BATCH * HEADS * (SEQ / 128), 256, 0, stream>>>(qkvb, bias, aout);
  gemm_bt<true><<<(BATCH * SEQ / 128) * (DIM / 128), 256, 0, stream>>>(
      aout, wout_t, d_out, BATCH * SEQ, DIM, INNER);
}

// Round 3
// 349.893 us; speedup vs baseline: 1.1225x; 1.1225x over previous
//
#include <hip/hip_runtime.h>

// ---------------------------------------------------------------------------
// BiasedAttention fused pipeline (MI355X / gfx950) — R3
//   R3: attn latency fix — K tile via global_load_lds dbuf (prefetch t+1,
//   swizzled), XCD-chunked block swizzle for bias L2 reuse, setprio on MFMA.
// Workspace layout (bytes):
//   xn      bf16  8192*1024*2  = 16777216   @ 0
//   wqkv_t  bf16  3072*1024*2  =  6291456   @ 16777216
//   wout_t  bf16  1024*1024*2  =  2097152   @ 23068672
//   qkv     bf16  8192*3072*2  = 50331648   @ 25165824
//   aout    bf16  8192*1024*2  = 16777216   @ 75497472
// ---------------------------------------------------------------------------

#define DIM    1024
#define HEADS  16
#define DHEAD  64
#define INNER  1024
#define SEQ    1024
#define BATCH  8
#define QKV3   3072

typedef __bf16 bf16x8 __attribute__((ext_vector_type(8)));
typedef float f32x4 __attribute__((ext_vector_type(4)));
typedef unsigned short u16x8 __attribute__((ext_vector_type(8)));
typedef unsigned short u16x4 __attribute__((ext_vector_type(4)));

typedef __attribute__((address_space(1))) const unsigned int as1_uint;
typedef __attribute__((address_space(3))) unsigned int as3_uint;

static __device__ inline unsigned short f2bf(float f) {
  unsigned int u = __float_as_uint(f);
  u = (u + 0x7FFFu + ((u >> 16) & 1u)) >> 16;  // RNE
  return (unsigned short)u;
}
static __device__ inline unsigned short f2bf_fast(float f) {
  __bf16 h = (__bf16)f;
  return __builtin_bit_cast(unsigned short, h);
}

// ---------------------------------------------------------------------------
// 1. LayerNorm fp32 -> bf16
// ---------------------------------------------------------------------------
__global__ __launch_bounds__(256) void ln_bf16_kernel(
    const float* __restrict__ x, const float* __restrict__ gamma,
    const float* __restrict__ beta, unsigned short* __restrict__ xn) {
  int row = blockIdx.x;
  int tid = threadIdx.x;
  const float4* xr = reinterpret_cast<const float4*>(x + (size_t)row * DIM);
  float4 v = xr[tid];
  float s = v.x + v.y + v.z + v.w;
  float s2 = v.x * v.x + v.y * v.y + v.z * v.z + v.w * v.w;
#pragma unroll
  for (int m = 32; m; m >>= 1) {
    s += __shfl_xor(s, m, 64);
    s2 += __shfl_xor(s2, m, 64);
  }
  __shared__ float red[2][4];
  int wid = tid >> 6, lane = tid & 63;
  if (lane == 0) { red[0][wid] = s; red[1][wid] = s2; }
  __syncthreads();
  s = red[0][0] + red[0][1] + red[0][2] + red[0][3];
  s2 = red[1][0] + red[1][1] + red[1][2] + red[1][3];
  float mu = s * (1.0f / DIM);
  float var = s2 * (1.0f / DIM) - mu * mu;
  float rstd = rsqrtf(var + 1e-5f);
  float4 g = reinterpret_cast<const float4*>(gamma)[tid];
  float4 b = reinterpret_cast<const float4*>(beta)[tid];
  u16x4 o;
  o[0] = f2bf((v.x - mu) * rstd * g.x + b.x);
  o[1] = f2bf((v.y - mu) * rstd * g.y + b.y);
  o[2] = f2bf((v.z - mu) * rstd * g.z + b.z);
  o[3] = f2bf((v.w - mu) * rstd * g.w + b.w);
  *reinterpret_cast<u16x4*>(xn + (size_t)row * DIM + tid * 4) = o;
}

// ---------------------------------------------------------------------------
// 2. Transpose + fp32->bf16:  W[R][C] -> Wt[C][R]; rows < scale_rows get *0.125
// ---------------------------------------------------------------------------
__global__ __launch_bounds__(256) void transpose_cvt(
    const float* __restrict__ W, unsigned short* __restrict__ Wt, int R, int C,
    int scale_rows) {
  __shared__ float tb[32][33];
  int c0 = blockIdx.x * 32, r0 = blockIdx.y * 32;
  int tx = threadIdx.x, ty = threadIdx.y;  // (32, 8)
#pragma unroll
  for (int i = 0; i < 4; ++i)
    tb[ty + i * 8][tx] = W[(size_t)(r0 + ty + i * 8) * C + c0 + tx];
  __syncthreads();
#pragma unroll
  for (int i = 0; i < 4; ++i) {
    int orow = c0 + ty + i * 8;
    float v = tb[tx][ty + i * 8];
    if (orow < scale_rows) v *= 0.125f;
    Wt[(size_t)orow * R + r0 + tx] = f2bf(v);
  }
}

// ---------------------------------------------------------------------------
// 3. GEMM  C[M,N] = A[M,K] @ Bt[N,K]^T   (bf16 in, fp32 acc) — m97 structure
// ---------------------------------------------------------------------------
template <bool F32OUT>
__global__ __launch_bounds__(256) void gemm_bt(
    const unsigned short* __restrict__ A, const unsigned short* __restrict__ Bt,
    void* __restrict__ Cout, int M, int N, int K) {
  __shared__ unsigned short As[128 * 64];
  __shared__ unsigned short Bs[128 * 64];
  int nb = N >> 7;
  int bm = blockIdx.x / nb, bn = blockIdx.x % nb;
  int tid = threadIdx.x, wid = tid >> 6, lane = tid & 63;
  int wr = wid >> 1, wc = wid & 1;
  int lg = lane >> 4, lr = lane & 15;
  f32x4 acc[4][4] = {};
  const unsigned short* Ablk = A + (size_t)(bm * 128) * K;
  const unsigned short* Bblk = Bt + (size_t)(bn * 128) * K;
  int srow = wid * 32 + (lane >> 3);
  int scol = (lane & 7) * 8;
  for (int kt = 0; kt < K; kt += 64) {
#pragma unroll
    for (int t = 0; t < 4; ++t) {
      int r = srow + t * 8;
      __builtin_amdgcn_global_load_lds(
          (as1_uint*)(Ablk + (size_t)r * K + kt + scol),
          (as3_uint*)(&As[(wid * 32 + t * 8) * 64]), 16, 0, 0);
      __builtin_amdgcn_global_load_lds(
          (as1_uint*)(Bblk + (size_t)r * K + kt + scol),
          (as3_uint*)(&Bs[(wid * 32 + t * 8) * 64]), 16, 0, 0);
    }
    __syncthreads();
#pragma unroll
    for (int kk = 0; kk < 2; ++kk) {
      bf16x8 af[4], bfr[4];
#pragma unroll
      for (int mi = 0; mi < 4; ++mi)
        af[mi] = *reinterpret_cast<const bf16x8*>(
            &As[(wr * 64 + mi * 16 + lr) * 64 + kk * 32 + lg * 8]);
#pragma unroll
      for (int ni = 0; ni < 4; ++ni)
        bfr[ni] = *reinterpret_cast<const bf16x8*>(
            &Bs[(wc * 64 + ni * 16 + lr) * 64 + kk * 32 + lg * 8]);
#pragma unroll
      for (int mi = 0; mi < 4; ++mi)
#pragma unroll
        for (int ni = 0; ni < 4; ++ni)
          acc[mi][ni] = __builtin_amdgcn_mfma_f32_16x16x32_bf16(
              af[mi], bfr[ni], acc[mi][ni], 0, 0, 0);
    }
    __syncthreads();
  }
#pragma unroll
  for (int mi = 0; mi < 4; ++mi) {
    int row = bm * 128 + wr * 64 + mi * 16 + lg * 4;
#pragma unroll
    for (int ni = 0; ni < 4; ++ni) {
      int col = bn * 128 + wc * 64 + ni * 16 + lr;
#pragma unroll
      for (int j = 0; j < 4; ++j) {
        if (F32OUT)
          ((float*)Cout)[(size_t)(row + j) * N + col] = acc[mi][ni][j];
        else
          ((unsigned short*)Cout)[(size_t)(row + j) * N + col] = f2bf(acc[mi][ni][j]);
      }
    }
  }
}

// ---------------------------------------------------------------------------
// 4. Flash attention, swapped-operand form (R3 latency-pipelined).
//    Per tile: V scatter (regs prefetched t-1) -> barrier (drains vmcnt:
//    K[t] stage done) -> issue K[t+1] global_load_lds (XOR-src-swizzled) +
//    V[t+1] reg loads -> bias loads -> QK^T from LDS (XOR read) -> softmax
//    (lane-local rows) -> P LDS -> PV. No global latency on critical path.
//    XCD-chunked block swizzle: 8 batches sharing a bias slice -> same L2.
// ---------------------------------------------------------------------------
__global__ __launch_bounds__(256) void attn_kernel(
    const unsigned short* __restrict__ qkv, const float* __restrict__ bias,
    unsigned short* __restrict__ aout) {
  int phys = blockIdx.x;
  int id = (phys & 7) * 128 + (phys >> 3);  // bijective: 1024 = 8*128
  int b = id & 7, qt = (id >> 3) & 7, h = id >> 6;
  int tid = threadIdx.x, wid = tid >> 6, lane = tid & 63;
  int lg = lane >> 4, lr = lane & 15;

  __shared__ unsigned short Ks[2][64 * 64];   // [kv][d] linear, XOR-swizzled
  __shared__ unsigned short Vt[2][64 * 72];   // [d][kv] transposed, dbuf
  __shared__ unsigned short Ps[4][32 * 72];   // per-wave P [q][kv]

  const unsigned short* qbase = qkv + (size_t)(b * SEQ) * QKV3 + h * 64;
  const unsigned short* kbase = qbase + INNER;
  const unsigned short* vbase = qbase + 2 * INNER;
  const float* biash = bias + (size_t)h * SEQ * SEQ;

  int q0 = qt * 128 + wid * 32;

  // Q fragments (B-operand: col=lr=q, k=d contiguous). Pre-scaled by 0.125.
  bf16x8 qf[2][2];
#pragma unroll
  for (int mi = 0; mi < 2; ++mi)
#pragma unroll
    for (int kk = 0; kk < 2; ++kk)
      qf[mi][kk] = *reinterpret_cast<const bf16x8*>(
          qbase + (size_t)(q0 + mi * 16 + lr) * QKV3 + kk * 32 + lg * 8);

  const float* brow[2];
#pragma unroll
  for (int mi = 0; mi < 2; ++mi)
    brow[mi] = biash + (size_t)(q0 + mi * 16 + lr) * SEQ;

  // staging indices
  int vrow = tid & 63;       // V: kv row
  int vchunk = tid >> 6;     // V: d chunk base
  int krow_in = lane >> 3;   // K: row-in-issue 0..7
  int kchunk = lane & 7;     // K: 16B chunk 0..7
  int kxor = lr & 7;         // K read-side XOR

  // ---- prologue: stage K[0], load V[0] regs ----
#pragma unroll
  for (int i = 0; i < 2; ++i) {
    int r = wid * 16 + i * 8 + krow_in;
    __builtin_amdgcn_global_load_lds(
        (as1_uint*)(kbase + (size_t)r * QKV3 + (kchunk ^ (r & 7)) * 8),
        (as3_uint*)(&Ks[0][(wid * 16 + i * 8) * 64]), 16, 0, 0);
  }
  u16x8 vreg[2];
#pragma unroll
  for (int it = 0; it < 2; ++it)
    vreg[it] = *reinterpret_cast<const u16x8*>(
        vbase + (size_t)vrow * QKV3 + (vchunk + it * 4) * 8);

  f32x4 oacc[2][4] = {};
  float mrun[2] = {-1e30f, -1e30f}, lrun[2] = {0.f, 0.f};

#define ATTN_STEP(TT, BUF, PREFETCH)                                           \
  {                                                                            \
    _Pragma("unroll") for (int it = 0; it < 2; ++it)                           \
        _Pragma("unroll") for (int i = 0; i < 8; ++i)                          \
            Vt[BUF][((vchunk + it * 4) * 8 + i) * 72 + vrow] = vreg[it][i];    \
    __syncthreads();                                                           \
    if (PREFETCH) {                                                            \
      _Pragma("unroll") for (int i = 0; i < 2; ++i) {                          \
        int r = wid * 16 + i * 8 + krow_in;                                    \
        __builtin_amdgcn_global_load_lds(                                      \
            (as1_uint*)(kbase + (size_t)(((TT) + 1) * 64 + r) * QKV3 +         \
                        (kchunk ^ (r & 7)) * 8),                               \
            (as3_uint*)(&Ks[1 - (BUF)][(wid * 16 + i * 8) * 64]), 16, 0, 0);   \
      }                                                                        \
      _Pragma("unroll") for (int it = 0; it < 2; ++it)                         \
          vreg[it] = *reinterpret_cast<const u16x8*>(                          \
              vbase + (size_t)(((TT) + 1) * 64 + vrow) * QKV3 +                \
              (vchunk + it * 4) * 8);                                          \
    }                                                                          \
    f32x4 bv[2][4];                                                            \
    _Pragma("unroll") for (int mi = 0; mi < 2; ++mi)                           \
        _Pragma("unroll") for (int kb = 0; kb < 4; ++kb)                       \
            bv[mi][kb] = *reinterpret_cast<const f32x4*>(                      \
                brow[mi] + (TT) * 64 + kb * 16 + lg * 4);                      \
    f32x4 s[2][4] = {};                                                        \
    const unsigned short* ksb = Ks[BUF];                                       \
    __builtin_amdgcn_s_setprio(1);                                             \
    _Pragma("unroll") for (int kb = 0; kb < 4; ++kb) {                         \
      int rowb = (kb * 16 + lr) * 64;                                          \
      bf16x8 k0 = *reinterpret_cast<const bf16x8*>(                            \
          ksb + rowb + ((lg ^ kxor) << 3));                                    \
      bf16x8 k1 = *reinterpret_cast<const bf16x8*>(                            \
          ksb + rowb + (((4 + lg) ^ kxor) << 3));                              \
      _Pragma("unroll") for (int mi = 0; mi < 2; ++mi) {                       \
        s[mi][kb] = __builtin_amdgcn_mfma_f32_16x16x32_bf16(                   \
            k0, qf[mi][0], s[mi][kb], 0, 0, 0);                                \
        s[mi][kb] = __builtin_amdgcn_mfma_f32_16x16x32_bf16(                   \
            k1, qf[mi][1], s[mi][kb], 0, 0, 0);                                \
      }                                                                        \
    }                                                                          \
    __builtin_amdgcn_s_setprio(0);                                             \
    _Pragma("unroll") for (int mi = 0; mi < 2; ++mi)                           \
        _Pragma("unroll") for (int kb = 0; kb < 4; ++kb)                       \
            _Pragma("unroll") for (int j = 0; j < 4; ++j)                      \
                s[mi][kb][j] += bv[mi][kb][j];                                 \
    float alpha[2];                                                            \
    _Pragma("unroll") for (int mi = 0; mi < 2; ++mi) {                         \
      float t0 = fmaxf(fmaxf(s[mi][0][0], s[mi][0][1]),                        \
                       fmaxf(s[mi][0][2], s[mi][0][3]));                       \
      float t1 = fmaxf(fmaxf(s[mi][1][0], s[mi][1][1]),                        \
                       fmaxf(s[mi][1][2], s[mi][1][3]));                       \
      float t2 = fmaxf(fmaxf(s[mi][2][0], s[mi][2][1]),                        \
                       fmaxf(s[mi][2][2], s[mi][2][3]));                       \
      float t3 = fmaxf(fmaxf(s[mi][3][0], s[mi][3][1]),                        \
                       fmaxf(s[mi][3][2], s[mi][3][3]));                       \
      float rm = fmaxf(fmaxf(t0, t1), fmaxf(t2, t3));                          \
      rm = fmaxf(rm, __shfl_xor(rm, 16, 64));                                  \
      rm = fmaxf(rm, __shfl_xor(rm, 32, 64));                                  \
      float mnew = fmaxf(mrun[mi], rm);                                        \
      alpha[mi] = __expf(mrun[mi] - mnew);                                     \
      mrun[mi] = mnew;                                                         \
      float ls = 0.f;                                                          \
      _Pragma("unroll") for (int kb = 0; kb < 4; ++kb) {                       \
        float e0 = __expf(s[mi][kb][0] - mnew);                                \
        float e1 = __expf(s[mi][kb][1] - mnew);                                \
        float e2 = __expf(s[mi][kb][2] - mnew);                                \
        float e3 = __expf(s[mi][kb][3] - mnew);                                \
        s[mi][kb][0] = e0; s[mi][kb][1] = e1;                                  \
        s[mi][kb][2] = e2; s[mi][kb][3] = e3;                                  \
        ls += (e0 + e1) + (e2 + e3);                                           \
      }                                                                        \
      ls += __shfl_xor(ls, 16, 64);                                            \
      ls += __shfl_xor(ls, 32, 64);                                            \
      lrun[mi] = lrun[mi] * alpha[mi] + ls;                                    \
    }                                                                          \
    _Pragma("unroll") for (int mi = 0; mi < 2; ++mi)                           \
        _Pragma("unroll") for (int kb = 0; kb < 4; ++kb) {                     \
      u16x4 pk;                                                                \
      pk[0] = f2bf_fast(s[mi][kb][0]);                                         \
      pk[1] = f2bf_fast(s[mi][kb][1]);                                         \
      pk[2] = f2bf_fast(s[mi][kb][2]);                                         \
      pk[3] = f2bf_fast(s[mi][kb][3]);                                         \
      *reinterpret_cast<u16x4*>(                                               \
          &Ps[wid][(mi * 16 + lr) * 72 + kb * 16 + lg * 4]) = pk;              \
    }                                                                          \
    asm volatile("s_waitcnt lgkmcnt(0)" ::: "memory");                         \
    __builtin_amdgcn_sched_barrier(0);                                         \
    _Pragma("unroll") for (int mi = 0; mi < 2; ++mi)                           \
        _Pragma("unroll") for (int db = 0; db < 4; ++db)                       \
            _Pragma("unroll") for (int j = 0; j < 4; ++j)                      \
                oacc[mi][db][j] *= alpha[mi];                                  \
    __builtin_amdgcn_s_setprio(1);                                             \
    _Pragma("unroll") for (int k2 = 0; k2 < 2; ++k2) {                         \
      bf16x8 va[4], pb[2];                                                     \
      _Pragma("unroll") for (int db = 0; db < 4; ++db)                         \
          va[db] = *reinterpret_cast<const bf16x8*>(                           \
              &Vt[BUF][(db * 16 + lr) * 72 + k2 * 32 + lg * 8]);               \
      _Pragma("unroll") for (int mi = 0; mi < 2; ++mi)                         \
          pb[mi] = *reinterpret_cast<const bf16x8*>(                           \
              &Ps[wid][(mi * 16 + lr) * 72 + k2 * 32 + lg * 8]);               \
      _Pragma("unroll") for (int mi = 0; mi < 2; ++mi)                         \
          _Pragma("unroll") for (int db = 0; db < 4; ++db)                     \
              oacc[mi][db] = __builtin_amdgcn_mfma_f32_16x16x32_bf16(          \
                  va[db], pb[mi], oacc[mi][db], 0, 0, 0);                      \
    }                                                                          \
    __builtin_amdgcn_s_setprio(0);                                             \
  }

  for (int t = 0; t < 16; t += 2) {
    ATTN_STEP(t, 0, true);
    ATTN_STEP(t + 1, 1, (t + 1) < 15);
  }
#undef ATTN_STEP

  // ---- epilogue: O^T / l -> aout bf16 ----
#pragma unroll
  for (int mi = 0; mi < 2; ++mi) {
    float inv = 1.0f / lrun[mi];
    size_t row = (size_t)(b * SEQ + q0 + mi * 16 + lr) * INNER + h * 64;
#pragma unroll
    for (int db = 0; db < 4; ++db) {
      u16x4 o;
      o[0] = f2bf_fast(oacc[mi][db][0] * inv);
      o[1] = f2bf_fast(oacc[mi][db][1] * inv);
      o[2] = f2bf_fast(oacc[mi][db][2] * inv);
      o[3] = f2bf_fast(oacc[mi][db][3] * inv);
      *reinterpret_cast<u16x4*>(&aout[row + db * 16 + lg * 4]) = o;
    }
  }
}

// ---------------------------------------------------------------------------
extern "C" void kernel_launch(void* const* d_in, const int* in_sizes, int n_in,
                              void* d_out, int out_size, void* d_ws, size_t ws_size,
                              hipStream_t stream) {
  const float* x = (const float*)d_in[0];
  const float* gamma = (const float*)d_in[1];
  const float* beta = (const float*)d_in[2];
  const float* w_qkv = (const float*)d_in[3];
  const float* w_out = (const float*)d_in[4];
  const float* bias = (const float*)d_in[5];

  char* ws = (char*)d_ws;
  unsigned short* xn = (unsigned short*)(ws);
  unsigned short* wqkv_t = (unsigned short*)(ws + 16777216);
  unsigned short* wout_t = (unsigned short*)(ws + 23068672);
  unsigned short* qkvb = (unsigned short*)(ws + 25165824);
  unsigned short* aout = (unsigned short*)(ws + 75497472);

  ln_bf16_kernel<<<BATCH * SEQ, 256, 0, stream>>>(x, gamma, beta, xn);
  transpose_cvt<<<dim3(QKV3 / 32, DIM / 32), dim3(32, 8), 0, stream>>>(
      w_qkv, wqkv_t, DIM, QKV3, INNER);
  transpose_cvt<<<dim3(DIM / 32, INNER / 32), dim3(32, 8), 0, stream>>>(
      w_out, wout_t, INNER, DIM, 0);
  gemm_bt<false><<<(BATCH * SEQ / 128) * (QKV3 / 128), 256, 0, stream>>>(
      xn, wqkv_t, (void*)qkvb, BATCH * SEQ, QKV3, DIM);
  attn_kernel<<<BATCH * HEADS * (SEQ / 128), 256, 0, stream>>>(qkvb, bias, aout);
  gemm_bt<true><<<(BATCH * SEQ / 128) * (DIM / 128), 256, 0, stream>>>(
      aout, wout_t, d_out, BATCH * SEQ, DIM, INNER);
}

// Round 5
// 335.759 us; speedup vs baseline: 1.1697x; 1.0421x over previous
//
#include <hip/hip_runtime.h>

// ---------------------------------------------------------------------------
// BiasedAttention fused pipeline (MI355X / gfx950) — R5 (= R4 + live vmcnt)
//   GEMMs: ring-3 counted-vmcnt schedule (BK=32, 3 LDS slots, stage kt+2
//   while computing kt, vmcnt(4) + RAW s_barrier (not __syncthreads, which
//   would re-insert vmcnt(0) and degenerate to drain-0), XOR chunk swizzle,
//   setprio, XCD-chunked block swizzle). attn unchanged from R3 (122 us).
// Workspace layout (bytes):
//   xn      bf16  8192*1024*2  = 16777216   @ 0
//   wqkv_t  bf16  3072*1024*2  =  6291456   @ 16777216
//   wout_t  bf16  1024*1024*2  =  2097152   @ 23068672
//   qkv     bf16  8192*3072*2  = 50331648   @ 25165824
//   aout    bf16  8192*1024*2  = 16777216   @ 75497472
// ---------------------------------------------------------------------------

#define DIM    1024
#define HEADS  16
#define DHEAD  64
#define INNER  1024
#define SEQ    1024
#define BATCH  8
#define QKV3   3072

typedef __bf16 bf16x8 __attribute__((ext_vector_type(8)));
typedef float f32x4 __attribute__((ext_vector_type(4)));
typedef unsigned short u16x8 __attribute__((ext_vector_type(8)));
typedef unsigned short u16x4 __attribute__((ext_vector_type(4)));

typedef __attribute__((address_space(1))) const unsigned int as1_uint;
typedef __attribute__((address_space(3))) unsigned int as3_uint;

static __device__ inline unsigned short f2bf(float f) {
  unsigned int u = __float_as_uint(f);
  u = (u + 0x7FFFu + ((u >> 16) & 1u)) >> 16;  // RNE
  return (unsigned short)u;
}
static __device__ inline unsigned short f2bf_fast(float f) {
  __bf16 h = (__bf16)f;
  return __builtin_bit_cast(unsigned short, h);
}

// ---------------------------------------------------------------------------
// 1. LayerNorm fp32 -> bf16
// ---------------------------------------------------------------------------
__global__ __launch_bounds__(256) void ln_bf16_kernel(
    const float* __restrict__ x, const float* __restrict__ gamma,
    const float* __restrict__ beta, unsigned short* __restrict__ xn) {
  int row = blockIdx.x;
  int tid = threadIdx.x;
  const float4* xr = reinterpret_cast<const float4*>(x + (size_t)row * DIM);
  float4 v = xr[tid];
  float s = v.x + v.y + v.z + v.w;
  float s2 = v.x * v.x + v.y * v.y + v.z * v.z + v.w * v.w;
#pragma unroll
  for (int m = 32; m; m >>= 1) {
    s += __shfl_xor(s, m, 64);
    s2 += __shfl_xor(s2, m, 64);
  }
  __shared__ float red[2][4];
  int wid = tid >> 6, lane = tid & 63;
  if (lane == 0) { red[0][wid] = s; red[1][wid] = s2; }
  __syncthreads();
  s = red[0][0] + red[0][1] + red[0][2] + red[0][3];
  s2 = red[1][0] + red[1][1] + red[1][2] + red[1][3];
  float mu = s * (1.0f / DIM);
  float var = s2 * (1.0f / DIM) - mu * mu;
  float rstd = rsqrtf(var + 1e-5f);
  float4 g = reinterpret_cast<const float4*>(gamma)[tid];
  float4 b = reinterpret_cast<const float4*>(beta)[tid];
  u16x4 o;
  o[0] = f2bf((v.x - mu) * rstd * g.x + b.x);
  o[1] = f2bf((v.y - mu) * rstd * g.y + b.y);
  o[2] = f2bf((v.z - mu) * rstd * g.z + b.z);
  o[3] = f2bf((v.w - mu) * rstd * g.w + b.w);
  *reinterpret_cast<u16x4*>(xn + (size_t)row * DIM + tid * 4) = o;
}

// ---------------------------------------------------------------------------
// 2. Transpose + fp32->bf16:  W[R][C] -> Wt[C][R]; rows < scale_rows get *0.125
// ---------------------------------------------------------------------------
__global__ __launch_bounds__(256) void transpose_cvt(
    const float* __restrict__ W, unsigned short* __restrict__ Wt, int R, int C,
    int scale_rows) {
  __shared__ float tb[32][33];
  int c0 = blockIdx.x * 32, r0 = blockIdx.y * 32;
  int tx = threadIdx.x, ty = threadIdx.y;  // (32, 8)
#pragma unroll
  for (int i = 0; i < 4; ++i)
    tb[ty + i * 8][tx] = W[(size_t)(r0 + ty + i * 8) * C + c0 + tx];
  __syncthreads();
#pragma unroll
  for (int i = 0; i < 4; ++i) {
    int orow = c0 + ty + i * 8;
    float v = tb[tx][ty + i * 8];
    if (orow < scale_rows) v *= 0.125f;
    Wt[(size_t)orow * R + r0 + tx] = f2bf(v);
  }
}

// ---------------------------------------------------------------------------
// 3. GEMM  C[M,N] = A[M,K] @ Bt[N,K]^T   (bf16 in, fp32 acc)
//    Ring-3: BK=32, slots {kt%3}; while computing kt, stage kt+2 into slot
//    (kt+2)%3 (never the slot being read, nor the next -> race-free by
//    construction; slot ss is read 2 iters later, after 2 vmcnt checkpoints).
//    Counted s_waitcnt vmcnt(4) + RAW s_barrier: each wave's own 4
//    newest stage-loads stay in flight across the barrier (T4). The asm
//    "memory" clobbers fence IR-level motion across the barrier.
//    Chunk swizzle c^=(row>>1)&3 (inverse on global src, rule #21).
// ---------------------------------------------------------------------------
template <bool F32OUT>
__global__ __launch_bounds__(256) void gemm_ring(
    const unsigned short* __restrict__ A, const unsigned short* __restrict__ Bt,
    void* __restrict__ Cout, int M, int N, int K) {
  __shared__ unsigned short As[3][128 * 32];
  __shared__ unsigned short Bs[3][128 * 32];
  int nb = N >> 7;
  int nwg = (M >> 7) * nb;
  int cpx = nwg >> 3;
  int phys = blockIdx.x;
  int swz = (phys & 7) * cpx + (phys >> 3);  // bijective (nwg % 8 == 0)
  int bm = swz / nb, bn = swz % nb;
  int tid = threadIdx.x, wid = tid >> 6, lane = tid & 63;
  int wr = wid >> 1, wc = wid & 1;
  int lg = lane >> 4, lr = lane & 15;
  const unsigned short* Ablk = A + (size_t)(bm * 128) * K;
  const unsigned short* Bblk = Bt + (size_t)(bn * 128) * K;

  // staging: wave wid covers LDS rows wid*32 .. wid*32+31 via two issues.
  // lane -> row sr0(+16), 16B chunk sc; global src chunk = sc ^ ((row>>1)&3).
  int sr0 = wid * 32 + (lane >> 2);
  int sc = lane & 3;
  int r0 = sr0, r1 = sr0 + 16;
  size_t aoff0 = (size_t)r0 * K + (sc ^ ((r0 >> 1) & 3)) * 8;
  size_t aoff1 = (size_t)r1 * K + (sc ^ ((r1 >> 1) & 3)) * 8;
  int ldst0 = (wid * 32) * 32;        // LDS element offset, issue 0
  int ldst1 = (wid * 32 + 16) * 32;   // issue 1
  int NT = K >> 5;

  // fragment-read chunk offset; (row>>1)&3 == (lr>>1)&3 for all frag rows.
  int rdc = (lg ^ ((lr >> 1) & 3)) * 8;

  f32x4 acc[4][4] = {};

  // ---- prologue: stage tiles 0 and 1 ----
#pragma unroll
  for (int t2 = 0; t2 < 2; ++t2) {
    __builtin_amdgcn_global_load_lds((as1_uint*)(Ablk + aoff0 + t2 * 32),
                                     (as3_uint*)(&As[t2][ldst0]), 16, 0, 0);
    __builtin_amdgcn_global_load_lds((as1_uint*)(Bblk + aoff0 + t2 * 32),
                                     (as3_uint*)(&Bs[t2][ldst0]), 16, 0, 0);
    __builtin_amdgcn_global_load_lds((as1_uint*)(Ablk + aoff1 + t2 * 32),
                                     (as3_uint*)(&As[t2][ldst1]), 16, 0, 0);
    __builtin_amdgcn_global_load_lds((as1_uint*)(Bblk + aoff1 + t2 * 32),
                                     (as3_uint*)(&Bs[t2][ldst1]), 16, 0, 0);
  }
  asm volatile("s_waitcnt vmcnt(4)" ::: "memory");  // tile 0 landed
  __builtin_amdgcn_s_barrier();
  asm volatile("" ::: "memory");

  int s0 = 0;
  for (int kt = 0; kt < NT; ++kt) {
    // ---- ds-read fragments of tile kt (slot s0) ----
    const unsigned short* as = As[s0];
    const unsigned short* bs = Bs[s0];
    bf16x8 a[4], b[4];
#pragma unroll
    for (int mi = 0; mi < 4; ++mi)
      a[mi] = *reinterpret_cast<const bf16x8*>(
          as + (wr * 64 + mi * 16 + lr) * 32 + rdc);
#pragma unroll
    for (int ni = 0; ni < 4; ++ni)
      b[ni] = *reinterpret_cast<const bf16x8*>(
          bs + (wc * 64 + ni * 16 + lr) * 32 + rdc);

    // ---- stage tile kt+2 (wrapped; tail reloads harmless) ----
    int st = kt + 2; if (st >= NT) st -= NT;
    int ss = s0 + 2; if (ss >= 3) ss -= 3;
    __builtin_amdgcn_global_load_lds((as1_uint*)(Ablk + aoff0 + st * 32),
                                     (as3_uint*)(&As[ss][ldst0]), 16, 0, 0);
    __builtin_amdgcn_global_load_lds((as1_uint*)(Bblk + aoff0 + st * 32),
                                     (as3_uint*)(&Bs[ss][ldst0]), 16, 0, 0);
    __builtin_amdgcn_global_load_lds((as1_uint*)(Ablk + aoff1 + st * 32),
                                     (as3_uint*)(&As[ss][ldst1]), 16, 0, 0);
    __builtin_amdgcn_global_load_lds((as1_uint*)(Bblk + aoff1 + st * 32),
                                     (as3_uint*)(&Bs[ss][ldst1]), 16, 0, 0);

    // ---- 16 MFMA (compiler inserts lgkmcnt for the ds_reads) ----
    __builtin_amdgcn_s_setprio(1);
#pragma unroll
    for (int mi = 0; mi < 4; ++mi)
#pragma unroll
      for (int ni = 0; ni < 4; ++ni)
        acc[mi][ni] = __builtin_amdgcn_mfma_f32_16x16x32_bf16(
            a[mi], b[ni], acc[mi][ni], 0, 0, 0);
    __builtin_amdgcn_s_setprio(0);

    // ---- counted checkpoint: tile kt+1 landed; kt+2's 4 stay in flight.
    //      RAW barrier (no vmcnt(0) re-drain). ds_reads of tile kt were
    //      consumed by the MFMAs above (compiler lgkm waits), so slot s0
    //      may be overwritten next iteration.
    asm volatile("s_waitcnt vmcnt(4)" ::: "memory");
    __builtin_amdgcn_s_barrier();
    asm volatile("" ::: "memory");
    s0 = (s0 == 2) ? 0 : s0 + 1;
  }

  // ---- epilogue: C write ----
#pragma unroll
  for (int mi = 0; mi < 4; ++mi) {
    int row = bm * 128 + wr * 64 + mi * 16 + lg * 4;
#pragma unroll
    for (int ni = 0; ni < 4; ++ni) {
      int col = bn * 128 + wc * 64 + ni * 16 + lr;
#pragma unroll
      for (int j = 0; j < 4; ++j) {
        if (F32OUT)
          ((float*)Cout)[(size_t)(row + j) * N + col] = acc[mi][ni][j];
        else
          ((unsigned short*)Cout)[(size_t)(row + j) * N + col] = f2bf(acc[mi][ni][j]);
      }
    }
  }
}

// ---------------------------------------------------------------------------
// 4. Flash attention, swapped-operand form (unchanged from measured R3).
// ---------------------------------------------------------------------------
__global__ __launch_bounds__(256) void attn_kernel(
    const unsigned short* __restrict__ qkv, const float* __restrict__ bias,
    unsigned short* __restrict__ aout) {
  int phys = blockIdx.x;
  int id = (phys & 7) * 128 + (phys >> 3);  // bijective: 1024 = 8*128
  int b = id & 7, qt = (id >> 3) & 7, h = id >> 6;
  int tid = threadIdx.x, wid = tid >> 6, lane = tid & 63;
  int lg = lane >> 4, lr = lane & 15;

  __shared__ unsigned short Ks[2][64 * 64];   // [kv][d] linear, XOR-swizzled
  __shared__ unsigned short Vt[2][64 * 72];   // [d][kv] transposed, dbuf
  __shared__ unsigned short Ps[4][32 * 72];   // per-wave P [q][kv]

  const unsigned short* qbase = qkv + (size_t)(b * SEQ) * QKV3 + h * 64;
  const unsigned short* kbase = qbase + INNER;
  const unsigned short* vbase = qbase + 2 * INNER;
  const float* biash = bias + (size_t)h * SEQ * SEQ;

  int q0 = qt * 128 + wid * 32;

  bf16x8 qf[2][2];
#pragma unroll
  for (int mi = 0; mi < 2; ++mi)
#pragma unroll
    for (int kk = 0; kk < 2; ++kk)
      qf[mi][kk] = *reinterpret_cast<const bf16x8*>(
          qbase + (size_t)(q0 + mi * 16 + lr) * QKV3 + kk * 32 + lg * 8);

  const float* brow[2];
#pragma unroll
  for (int mi = 0; mi < 2; ++mi)
    brow[mi] = biash + (size_t)(q0 + mi * 16 + lr) * SEQ;

  int vrow = tid & 63;
  int vchunk = tid >> 6;
  int krow_in = lane >> 3;
  int kchunk = lane & 7;
  int kxor = lr & 7;

#pragma unroll
  for (int i = 0; i < 2; ++i) {
    int r = wid * 16 + i * 8 + krow_in;
    __builtin_amdgcn_global_load_lds(
        (as1_uint*)(kbase + (size_t)r * QKV3 + (kchunk ^ (r & 7)) * 8),
        (as3_uint*)(&Ks[0][(wid * 16 + i * 8) * 64]), 16, 0, 0);
  }
  u16x8 vreg[2];
#pragma unroll
  for (int it = 0; it < 2; ++it)
    vreg[it] = *reinterpret_cast<const u16x8*>(
        vbase + (size_t)vrow * QKV3 + (vchunk + it * 4) * 8);

  f32x4 oacc[2][4] = {};
  float mrun[2] = {-1e30f, -1e30f}, lrun[2] = {0.f, 0.f};

#define ATTN_STEP(TT, BUF, PREFETCH)                                           \
  {                                                                            \
    _Pragma("unroll") for (int it = 0; it < 2; ++it)                           \
        _Pragma("unroll") for (int i = 0; i < 8; ++i)                          \
            Vt[BUF][((vchunk + it * 4) * 8 + i) * 72 + vrow] = vreg[it][i];    \
    __syncthreads();                                                           \
    if (PREFETCH) {                                                            \
      _Pragma("unroll") for (int i = 0; i < 2; ++i) {                          \
        int r = wid * 16 + i * 8 + krow_in;                                    \
        __builtin_amdgcn_global_load_lds(                                      \
            (as1_uint*)(kbase + (size_t)(((TT) + 1) * 64 + r) * QKV3 +         \
                        (kchunk ^ (r & 7)) * 8),                               \
            (as3_uint*)(&Ks[1 - (BUF)][(wid * 16 + i * 8) * 64]), 16, 0, 0);   \
      }                                                                        \
      _Pragma("unroll") for (int it = 0; it < 2; ++it)                         \
          vreg[it] = *reinterpret_cast<const u16x8*>(                          \
              vbase + (size_t)(((TT) + 1) * 64 + vrow) * QKV3 +                \
              (vchunk + it * 4) * 8);                                          \
    }                                                                          \
    f32x4 bv[2][4];                                                            \
    _Pragma("unroll") for (int mi = 0; mi < 2; ++mi)                           \
        _Pragma("unroll") for (int kb = 0; kb < 4; ++kb)                       \
            bv[mi][kb] = *reinterpret_cast<const f32x4*>(                      \
                brow[mi] + (TT) * 64 + kb * 16 + lg * 4);                      \
    f32x4 s[2][4] = {};                                                        \
    const unsigned short* ksb = Ks[BUF];                                       \
    __builtin_amdgcn_s_setprio(1);                                             \
    _Pragma("unroll") for (int kb = 0; kb < 4; ++kb) {                         \
      int rowb = (kb * 16 + lr) * 64;                                          \
      bf16x8 k0 = *reinterpret_cast<const bf16x8*>(                            \
          ksb + rowb + ((lg ^ kxor) << 3));                                    \
      bf16x8 k1 = *reinterpret_cast<const bf16x8*>(                            \
          ksb + rowb + (((4 + lg) ^ kxor) << 3));                              \
      _Pragma("unroll") for (int mi = 0; mi < 2; ++mi) {                       \
        s[mi][kb] = __builtin_amdgcn_mfma_f32_16x16x32_bf16(                   \
            k0, qf[mi][0], s[mi][kb], 0, 0, 0);                                \
        s[mi][kb] = __builtin_amdgcn_mfma_f32_16x16x32_bf16(                   \
            k1, qf[mi][1], s[mi][kb], 0, 0, 0);                                \
      }                                                                        \
    }                                                                          \
    __builtin_amdgcn_s_setprio(0);                                             \
    _Pragma("unroll") for (int mi = 0; mi < 2; ++mi)                           \
        _Pragma("unroll") for (int kb = 0; kb < 4; ++kb)                       \
            _Pragma("unroll") for (int j = 0; j < 4; ++j)                      \
                s[mi][kb][j] += bv[mi][kb][j];                                 \
    float alpha[2];                                                            \
    _Pragma("unroll") for (int mi = 0; mi < 2; ++mi) {                         \
      float t0 = fmaxf(fmaxf(s[mi][0][0], s[mi][0][1]),                        \
                       fmaxf(s[mi][0][2], s[mi][0][3]));                       \
      float t1 = fmaxf(fmaxf(s[mi][1][0], s[mi][1][1]),                        \
                       fmaxf(s[mi][1][2], s[mi][1][3]));                       \
      float t2 = fmaxf(fmaxf(s[mi][2][0], s[mi][2][1]),                        \
                       fmaxf(s[mi][2][2], s[mi][2][3]));                       \
      float t3 = fmaxf(fmaxf(s[mi][3][0], s[mi][3][1]),                        \
                       fmaxf(s[mi][3][2], s[mi][3][3]));                       \
      float rm = fmaxf(fmaxf(t0, t1), fmaxf(t2, t3));                          \
      rm = fmaxf(rm, __shfl_xor(rm, 16, 64));                                  \
      rm = fmaxf(rm, __shfl_xor(rm, 32, 64));                                  \
      float mnew = fmaxf(mrun[mi], rm);                                        \
      alpha[mi] = __expf(mrun[mi] - mnew);                                     \
      mrun[mi] = mnew;                                                         \
      float ls = 0.f;                                                          \
      _Pragma("unroll") for (int kb = 0; kb < 4; ++kb) {                       \
        float e0 = __expf(s[mi][kb][0] - mnew);                                \
        float e1 = __expf(s[mi][kb][1] - mnew);                                \
        float e2 = __expf(s[mi][kb][2] - mnew);                                \
        float e3 = __expf(s[mi][kb][3] - mnew);                                \
        s[mi][kb][0] = e0; s[mi][kb][1] = e1;                                  \
        s[mi][kb][2] = e2; s[mi][kb][3] = e3;                                  \
        ls += (e0 + e1) + (e2 + e3);                                           \
      }                                                                        \
      ls += __shfl_xor(ls, 16, 64);                                            \
      ls += __shfl_xor(ls, 32, 64);                                            \
      lrun[mi] = lrun[mi] * alpha[mi] + ls;                                    \
    }                                                                          \
    _Pragma("unroll") for (int mi = 0; mi < 2; ++mi)                           \
        _Pragma("unroll") for (int kb = 0; kb < 4; ++kb) {                     \
      u16x4 pk;                                                                \
      pk[0] = f2bf_fast(s[mi][kb][0]);                                         \
      pk[1] = f2bf_fast(s[mi][kb][1]);                                         \
      pk[2] = f2bf_fast(s[mi][kb][2]);                                         \
      pk[3] = f2bf_fast(s[mi][kb][3]);                                         \
      *reinterpret_cast<u16x4*>(                                               \
          &Ps[wid][(mi * 16 + lr) * 72 + kb * 16 + lg * 4]) = pk;              \
    }                                                                          \
    asm volatile("s_waitcnt lgkmcnt(0)" ::: "memory");                         \
    __builtin_amdgcn_sched_barrier(0);                                         \
    _Pragma("unroll") for (int mi = 0; mi < 2; ++mi)                           \
        _Pragma("unroll") for (int db = 0; db < 4; ++db)                       \
            _Pragma("unroll") for (int j = 0; j < 4; ++j)                      \
                oacc[mi][db][j] *= alpha[mi];                                  \
    __builtin_amdgcn_s_setprio(1);                                             \
    _Pragma("unroll") for (int k2 = 0; k2 < 2; ++k2) {                         \
      bf16x8 va[4], pb[2];                                                     \
      _Pragma("unroll") for (int db = 0; db < 4; ++db)                         \
          va[db] = *reinterpret_cast<const bf16x8*>(                           \
              &Vt[BUF][(db * 16 + lr) * 72 + k2 * 32 + lg * 8]);               \
      _Pragma("unroll") for (int mi = 0; mi < 2; ++mi)                         \
          pb[mi] = *reinterpret_cast<const bf16x8*>(                           \
              &Ps[wid][(mi * 16 + lr) * 72 + k2 * 32 + lg * 8]);               \
      _Pragma("unroll") for (int mi = 0; mi < 2; ++mi)                         \
          _Pragma("unroll") for (int db = 0; db < 4; ++db)                     \
              oacc[mi][db] = __builtin_amdgcn_mfma_f32_16x16x32_bf16(          \
                  va[db], pb[mi], oacc[mi][db], 0, 0, 0);                      \
    }                                                                          \
    __builtin_amdgcn_s_setprio(0);                                             \
  }

  for (int t = 0; t < 16; t += 2) {
    ATTN_STEP(t, 0, true);
    ATTN_STEP(t + 1, 1, (t + 1) < 15);
  }
#undef ATTN_STEP

#pragma unroll
  for (int mi = 0; mi < 2; ++mi) {
    float inv = 1.0f / lrun[mi];
    size_t row = (size_t)(b * SEQ + q0 + mi * 16 + lr) * INNER + h * 64;
#pragma unroll
    for (int db = 0; db < 4; ++db) {
      u16x4 o;
      o[0] = f2bf_fast(oacc[mi][db][0] * inv);
      o[1] = f2bf_fast(oacc[mi][db][1] * inv);
      o[2] = f2bf_fast(oacc[mi][db][2] * inv);
      o[3] = f2bf_fast(oacc[mi][db][3] * inv);
      *reinterpret_cast<u16x4*>(&aout[row + db * 16 + lg * 4]) = o;
    }
  }
}

// ---------------------------------------------------------------------------
extern "C" void kernel_launch(void* const* d_in, const int* in_sizes, int n_in,
                              void* d_out, int out_size, void* d_ws, size_t ws_size,
                              hipStream_t stream) {
  const float* x = (const float*)d_in[0];
  const float* gamma = (const float*)d_in[1];
  const float* beta = (const float*)d_in[2];
  const float* w_qkv = (const float*)d_in[3];
  const float* w_out = (const float*)d_in[4];
  const float* bias = (const float*)d_in[5];

  char* ws = (char*)d_ws;
  unsigned short* xn = (unsigned short*)(ws);
  unsigned short* wqkv_t = (unsigned short*)(ws + 16777216);
  unsigned short* wout_t = (unsigned short*)(ws + 23068672);
  unsigned short* qkvb = (unsigned short*)(ws + 25165824);
  unsigned short* aout = (unsigned short*)(ws + 75497472);

  ln_bf16_kernel<<<BATCH * SEQ, 256, 0, stream>>>(x, gamma, beta, xn);
  transpose_cvt<<<dim3(QKV3 / 32, DIM / 32), dim3(32, 8), 0, stream>>>(
      w_qkv, wqkv_t, DIM, QKV3, INNER);
  transpose_cvt<<<dim3(DIM / 32, INNER / 32), dim3(32, 8), 0, stream>>>(
      w_out, wout_t, INNER, DIM, 0);
  gemm_ring<false><<<(BATCH * SEQ / 128) * (QKV3 / 128), 256, 0, stream>>>(
      xn, wqkv_t, (void*)qkvb, BATCH * SEQ, QKV3, DIM);
  attn_kernel<<<BATCH * HEADS * (SEQ / 128), 256, 0, stream>>>(qkvb, bias, aout);
  gemm_ring<true><<<(BATCH * SEQ / 128) * (DIM / 128), 256, 0, stream>>>(
      aout, wout_t, d_out, BATCH * SEQ, DIM, INNER);
}